// Round 5
// baseline (58.490 us; speedup 1.0000x reference)
//
#include <hip/hip_runtime.h>

// CompositeBezierCurve: K=4096 segments, degree-7 Bezier (8 cp), D=3.
//   xt  = mod(x_eval[i], x[K]);  seg = searchsorted_right(xstart, xt) - 1
//   s   = (xt - x[seg]) / (x[seg+1] - x[seg]);  out = sum_j B_j(s) cp[seg][j]
//
// R4: VALU diet on top of R3's scalar-per-lane layout.
//  - fmodf -> exact conditional subtract (xe < 2*xlast always; Sterbenz exact)
//  - Bernstein weights -> precomputed per-(seg,d) MONOMIAL coeffs (f32),
//    evaluation = 7-fma Horner. No fp16 conversions at all.
//  - cm rows 128B-aligned: [seg][d][8] f32; 3 lanes of an eval span 2 lines.

constexpr int K_SEG = 4096;
constexpr int M_TAB = 16384;

struct __align__(16) Bucket { float xb, xlo0, xhi1; unsigned int segs; };

__device__ inline int ans_search(const float* __restrict__ x, float v) {
    // largest i in [0, K_SEG-1] with x[i] <= v  (x[0]=0, so v<0 -> 0)
    int lo = 0, hi = K_SEG - 1;
    while (lo < hi) {
        int mid = (lo + hi + 1) >> 1;
        if (x[mid] <= v) lo = mid; else hi = mid - 1;
    }
    return lo;
}

__global__ void build_table_kernel(const float* __restrict__ x,
                                   Bucket* __restrict__ tab) {
    int b = blockIdx.x * blockDim.x + threadIdx.x;
    if (b >= M_TAB) return;
    float xlast = x[K_SEG];
    float wq = xlast / (float)M_TAB;          // <= 0.375 since xlast <= 1.5*4096
    float delta = xlast * 2e-6f;              // >> rounding of xt*inv at eval time
    float vlo = (float)b * wq - delta;
    float vhi = ((float)b + 1.0f) * wq + delta;
    int slo = ans_search(x, vlo);
    int shi = ans_search(x, vhi);
    if (shi > slo + 1) shi = slo + 1;         // impossible (dx>=0.5); defensive
    Bucket e;
    if (shi > slo) {
        e.xb = x[shi]; e.xlo0 = x[slo]; e.xhi1 = x[shi + 1];
        e.segs = ((unsigned)shi << 16) | (unsigned)slo;
    } else {
        e.xb = x[slo]; e.xlo0 = x[slo]; e.xhi1 = x[slo + 1];
        e.segs = ((unsigned)slo << 16) | (unsigned)slo;
    }
    tab[b] = e;
}

// cp (K,8,3) f32 -> monomial coeffs cm[seg*32 + d*8 + j] (f32, 128B rows):
//   p(s) = sum_j cm_j s^j,  cm_j = C(7,j) * (forward_diff^j p)(0)
__global__ void convert_cm_kernel(const float* __restrict__ cp,
                                  float* __restrict__ cm) {
    int i = blockIdx.x * blockDim.x + threadIdx.x;   // (seg,d) pair
    if (i >= K_SEG * 3) return;
    int seg = i / 3, d = i - seg * 3;
    float t[8];
    #pragma unroll
    for (int j = 0; j < 8; ++j) t[j] = cp[seg * 24 + j * 3 + d];
    const float comb[8] = {1.f, 7.f, 21.f, 35.f, 35.f, 21.f, 7.f, 1.f};
    float* row = cm + (seg << 5) + (d << 3);
    row[0] = t[0];
    #pragma unroll
    for (int r = 1; r < 8; ++r) {
        #pragma unroll
        for (int k = 0; k < 7; ++k) t[k] = t[k + 1] - t[k];  // forward diff
        row[r] = comb[r] * t[0];
    }
}

__global__ __launch_bounds__(256) void bezier_eval_horner(
    const float* __restrict__ x,
    const Bucket* __restrict__ tab,
    const float* __restrict__ cm,
    const float* __restrict__ xe,
    float* __restrict__ out,
    int nscalar)
{
    const float xlast = x[K_SEG];
    const float inv = (float)M_TAB / xlast;
    const int tstride = gridDim.x * blockDim.x;
    const float4* __restrict__ tab4 = reinterpret_cast<const float4*>(tab);

    for (int base = blockIdx.x * blockDim.x + threadIdx.x; base < nscalar;
         base += tstride * 4) {
        #pragma unroll
        for (int v = 0; v < 4; ++v) {
            int i = base + v * tstride;
            int ic = (i < nscalar) ? i : (nscalar - 1);
            int e = ic / 3;                  // magic-mul
            int d = ic - e * 3;

            float xev = xe[e];
            float xt = (xev >= xlast) ? (xev - xlast) : xev;  // exact np.mod here

            int b = (int)(xt * inv);
            b = (b < M_TAB - 1) ? b : (M_TAB - 1);
            float4 ev = tab4[b];             // 3 lanes/eval share this line
            unsigned segs = __float_as_uint(ev.w);
            bool hi = (xt >= ev.x);
            int seg   = hi ? (int)(segs >> 16) : (int)(segs & 0xffffu);
            float x0  = hi ? ev.x : ev.y;
            float x1  = hi ? ev.z : ev.x;

            float s = (xt - x0) / (x1 - x0);

            // 32B: monomial coeffs of (seg, d); 3 lanes of this eval span
            // exactly 2 cache lines of the 128B-aligned row
            const float4* rowp = reinterpret_cast<const float4*>(cm + (seg << 5) + (d << 3));
            float4 c0 = rowp[0];
            float4 c1 = rowp[1];

            float a = c1.w;
            a = fmaf(a, s, c1.z);
            a = fmaf(a, s, c1.y);
            a = fmaf(a, s, c1.x);
            a = fmaf(a, s, c0.w);
            a = fmaf(a, s, c0.z);
            a = fmaf(a, s, c0.y);
            a = fmaf(a, s, c0.x);

            if (i < nscalar) out[i] = a;
        }
    }
}

// Fallback (ws too small): LDS binary search, f32 cp straight from inputs.
__global__ __launch_bounds__(256) void bezier_eval_fallback(
    const float* __restrict__ x,
    const float* __restrict__ cp,
    const float* __restrict__ xe,
    float* __restrict__ out,
    int n)
{
    __shared__ float xs[K_SEG + 1];
    for (int i = threadIdx.x; i < K_SEG + 1; i += blockDim.x) xs[i] = x[i];
    __syncthreads();
    const float xlast = xs[K_SEG];
    const int tstride = gridDim.x * blockDim.x;
    for (int i = blockIdx.x * blockDim.x + threadIdx.x; i < n; i += tstride) {
        float xt = fmodf(xe[i], xlast);
        int lo = 0, hi = K_SEG - 1;
        while (lo < hi) {
            int mid = (lo + hi + 1) >> 1;
            if (xs[mid] <= xt) lo = mid; else hi = mid - 1;
        }
        int seg = lo;
        float x0 = xs[seg];
        float s  = (xt - x0) / (xs[seg + 1] - x0);
        float ts = 1.0f - s;
        float comb[8] = {1.f, 7.f, 21.f, 35.f, 35.f, 21.f, 7.f, 1.f};
        float a0 = 0.f, a1 = 0.f, a2 = 0.f;
        float sp = 1.f;
        float tp[8];
        tp[7] = 1.f;
        for (int j = 6; j >= 0; --j) tp[j] = tp[j + 1] * ts;
        for (int j = 0; j < 8; ++j) {
            float wj = comb[j] * sp * tp[j];
            a0 = fmaf(wj, cp[seg * 24 + j * 3 + 0], a0);
            a1 = fmaf(wj, cp[seg * 24 + j * 3 + 1], a1);
            a2 = fmaf(wj, cp[seg * 24 + j * 3 + 2], a2);
            sp *= s;
        }
        out[i * 3 + 0] = a0;
        out[i * 3 + 1] = a1;
        out[i * 3 + 2] = a2;
    }
}

extern "C" void kernel_launch(void* const* d_in, const int* in_sizes, int n_in,
                              void* d_out, int out_size, void* d_ws, size_t ws_size,
                              hipStream_t stream) {
    const float* x  = (const float*)d_in[0];   // (K+1,)
    const float* cp = (const float*)d_in[1];   // (K, 8, 3)
    const float* xe = (const float*)d_in[2];   // (N_EVAL,)
    float* out = (float*)d_out;                // (N_EVAL, 3)
    int n = in_sizes[2];

    const size_t tab_bytes = (size_t)M_TAB * sizeof(Bucket);      // 256 KB
    const size_t cm_bytes  = (size_t)K_SEG * 32 * sizeof(float);  // 512 KB

    if (ws_size >= tab_bytes + cm_bytes) {
        Bucket* tab = (Bucket*)d_ws;
        float* cm   = (float*)((char*)d_ws + tab_bytes);
        build_table_kernel<<<(M_TAB + 255) / 256, 256, 0, stream>>>(x, tab);
        convert_cm_kernel<<<(K_SEG * 3 + 255) / 256, 256, 0, stream>>>(cp, cm);
        int nscalar = n * 3;
        bezier_eval_horner<<<4096, 256, 0, stream>>>(x, tab, cm, xe, out, nscalar);
    } else {
        bezier_eval_fallback<<<2048, 256, 0, stream>>>(x, cp, xe, out, n);
    }
}

// Round 6
// 48.834 us; speedup vs baseline: 1.1977x; 1.1977x over previous
//
#include <hip/hip_runtime.h>
#include <hip/hip_fp16.h>

// CompositeBezierCurve: K=4096 segments, degree-7 Bezier (8 cp), D=3.
//   xt  = mod(x_eval[i], x[K]);  seg = searchsorted_right(xstart, xt) - 1
//   s   = (xt - x[seg]) / (x[seg+1] - x[seg]);  out = sum_j B_j(s) cp[seg][j]
//
// R5: ONE scattered 64B line per eval.
//  - bucket table (16K x 8B {xb, lo, hi}) lives in LDS (128KB) -> segment
//    resolution uses the LDS pipe, not the TA/L1 path.
//  - seg-line table: 64B per segment = {f32 x0, f32 invdx, 24 x fp16 cp}:
//    the whole eval needs exactly one cache line (4 dwordx4, same line).
//  - eval-per-lane, 4-eval unroll, coalesced xe loads + float4 out stores,
//    exact conditional-subtract mod (xe < 2*xlast always).

constexpr int K_SEG = 4096;
constexpr int M_BKT = 16384;   // bucket width <= 0.375 < min dx 0.5 => <=1 knot

struct __align__(8) BEntry { float xb; unsigned short lo, hi; };

__device__ inline int ans_search(const float* __restrict__ x, float v) {
    // largest i in [0, K_SEG-1] with x[i] <= v  (x[0]=0, so v<0 -> 0)
    int lo = 0, hi = K_SEG - 1;
    while (lo < hi) {
        int mid = (lo + hi + 1) >> 1;
        if (x[mid] <= v) lo = mid; else hi = mid - 1;
    }
    return lo;
}

__global__ void build_bucket_kernel(const float* __restrict__ x,
                                    BEntry* __restrict__ btab) {
    int b = blockIdx.x * blockDim.x + threadIdx.x;
    if (b >= M_BKT) return;
    float xlast = x[K_SEG];
    float wq = xlast / (float)M_BKT;          // <= 0.375
    float delta = xlast * 2e-6f;              // >> eval-time rounding of xt*inv
    float vlo = (float)b * wq - delta;
    float vhi = ((float)b + 1.0f) * wq + delta;
    int slo = ans_search(x, vlo);
    int shi = ans_search(x, vhi);
    if (shi > slo + 1) shi = slo + 1;         // impossible (window < min dx); defensive
    BEntry e;
    e.lo = (unsigned short)slo;
    e.hi = (unsigned short)shi;
    e.xb = (shi > slo) ? x[shi] : 3.4e38f;    // boundary knot (or +inf if none)
    btab[b] = e;
}

// seg-line: 64B = {f32 x0, f32 invdx, fp16 cp[24] in natural (j,d) order, pad}
__global__ void build_segline_kernel(const float* __restrict__ x,
                                     const float* __restrict__ cp,
                                     float4* __restrict__ segt) {
    int s = blockIdx.x * blockDim.x + threadIdx.x;
    if (s >= K_SEG) return;
    float4 q[4];
    float* qf = reinterpret_cast<float*>(q);
    float x0 = x[s], x1 = x[s + 1];
    qf[0] = x0;
    qf[1] = 1.0f / (x1 - x0);
    __half* hh = reinterpret_cast<__half*>(qf + 2);
    #pragma unroll
    for (int r = 0; r < 24; ++r) hh[r] = __float2half(cp[s * 24 + r]);
    qf[14] = 0.f; qf[15] = 0.f;               // pad bytes 56..64
    #pragma unroll
    for (int k = 0; k < 4; ++k) segt[s * 4 + k] = q[k];
}

__global__ __launch_bounds__(1024) void bezier_eval_line(
    const float* __restrict__ x,
    const BEntry* __restrict__ gbtab,
    const float4* __restrict__ segt,
    const float* __restrict__ xe,
    float* __restrict__ out,
    int n)
{
    __shared__ BEntry bkt[M_BKT];             // 128 KB

    // stage bucket table into LDS (coalesced float4 copies)
    {
        const float4* g = reinterpret_cast<const float4*>(gbtab);
        float4* l = reinterpret_cast<float4*>(bkt);
        for (int i = threadIdx.x; i < M_BKT / 2; i += blockDim.x) l[i] = g[i];
    }
    __syncthreads();

    const float xlast = x[K_SEG];
    const float inv = (float)M_BKT / xlast;

    const int nquad = n >> 2;
    const int tstride = gridDim.x * blockDim.x;

    for (int t = blockIdx.x * blockDim.x + threadIdx.x; t < nquad; t += tstride) {
        float4 xv = reinterpret_cast<const float4*>(xe)[t];
        float xev[4] = {xv.x, xv.y, xv.z, xv.w};
        float r[12];

        #pragma unroll
        for (int e = 0; e < 4; ++e) {
            float xv1 = xev[e];
            float xt = (xv1 >= xlast) ? (xv1 - xlast) : xv1;  // exact np.mod here

            int b = (int)(xt * inv);
            b = (b < M_BKT - 1) ? b : (M_BKT - 1);
            BEntry be = bkt[b];                                // LDS, 8B
            int seg = (xt >= be.xb) ? (int)be.hi : (int)be.lo;

            // the ONE scattered line: 4 x dwordx4, same 64B line
            const float4* L = segt + (seg << 2);
            float4 q0 = L[0], q1 = L[1], q2 = L[2], q3 = L[3];

            float x0 = q0.x;
            float s  = (xt - x0) * q0.y;
            float ts = 1.0f - s;

            float w[8];
            {
                float s2 = s * s,  s3 = s2 * s,  s4 = s3 * s,  s5 = s4 * s,  s6 = s5 * s,  s7 = s6 * s;
                float t2 = ts * ts, t3 = t2 * ts, t4 = t3 * ts, t5 = t4 * ts, t6 = t5 * ts, t7 = t6 * ts;
                w[0] = t7;
                w[1] = 7.0f  * s  * t6;
                w[2] = 21.0f * s2 * t5;
                w[3] = 35.0f * s3 * t4;
                w[4] = 35.0f * s4 * t3;
                w[5] = 21.0f * s5 * t2;
                w[6] = 7.0f  * s6 * ts;
                w[7] = s7;
            }

            // unpack 24 fp16 cps from bytes 8..56 of the line
            float4 qb[4] = {q0, q1, q2, q3};
            const __half2* hh = reinterpret_cast<const __half2*>(
                reinterpret_cast<const char*>(qb) + 8);
            float a0 = 0.f, a1 = 0.f, a2 = 0.f;
            #pragma unroll
            for (int j = 0; j < 4; ++j) {   // 12 half2 = 24 floats = 8 cps x 3 dims
                float2 f0 = __half22float2(hh[3 * j + 0]);
                float2 f1 = __half22float2(hh[3 * j + 1]);
                float2 f2 = __half22float2(hh[3 * j + 2]);
                // cps 2j and 2j+1: (f0.x,f0.y,f1.x) and (f1.y,f2.x,f2.y)
                float w0 = w[2 * j], w1 = w[2 * j + 1];
                a0 = fmaf(w0, f0.x, a0);
                a1 = fmaf(w0, f0.y, a1);
                a2 = fmaf(w0, f1.x, a2);
                a0 = fmaf(w1, f1.y, a0);
                a1 = fmaf(w1, f2.x, a1);
                a2 = fmaf(w1, f2.y, a2);
            }
            r[e * 3 + 0] = a0;
            r[e * 3 + 1] = a1;
            r[e * 3 + 2] = a2;
        }

        float4* o4 = reinterpret_cast<float4*>(out + (size_t)t * 12);
        o4[0] = make_float4(r[0], r[1],  r[2],  r[3]);
        o4[1] = make_float4(r[4], r[5],  r[6],  r[7]);
        o4[2] = make_float4(r[8], r[9],  r[10], r[11]);
    }

    // scalar tail (n % 4 != 0 — defensive; n is 4M here)
    int tail_start = (n >> 2) << 2;
    if (blockIdx.x == 0 && threadIdx.x < (n - tail_start)) {
        int i = tail_start + threadIdx.x;
        float xt = fmodf(xe[i], xlast);
        int b = (int)(xt * inv);
        b = (b < M_BKT - 1) ? b : (M_BKT - 1);
        BEntry be = bkt[b];
        int seg = (xt >= be.xb) ? (int)be.hi : (int)be.lo;
        const float4* L = segt + (seg << 2);
        float4 q0 = L[0], q1 = L[1], q2 = L[2], q3 = L[3];
        float s  = (xt - q0.x) * q0.y;
        float ts = 1.0f - s;
        float comb[8] = {1.f, 7.f, 21.f, 35.f, 35.f, 21.f, 7.f, 1.f};
        float4 qb[4] = {q0, q1, q2, q3};
        const __half* hp = reinterpret_cast<const __half*>(
            reinterpret_cast<const char*>(qb) + 8);
        float sp = 1.f;
        float tp[8];
        tp[7] = 1.f;
        for (int j = 6; j >= 0; --j) tp[j] = tp[j + 1] * ts;
        float a0 = 0.f, a1 = 0.f, a2 = 0.f;
        for (int j = 0; j < 8; ++j) {
            float wj = comb[j] * sp * tp[j];
            a0 = fmaf(wj, __half2float(hp[j * 3 + 0]), a0);
            a1 = fmaf(wj, __half2float(hp[j * 3 + 1]), a1);
            a2 = fmaf(wj, __half2float(hp[j * 3 + 2]), a2);
            sp *= s;
        }
        out[i * 3 + 0] = a0;
        out[i * 3 + 1] = a1;
        out[i * 3 + 2] = a2;
    }
}

// Fallback (ws too small): LDS binary search, f32 cp straight from inputs.
__global__ __launch_bounds__(256) void bezier_eval_fallback(
    const float* __restrict__ x,
    const float* __restrict__ cp,
    const float* __restrict__ xe,
    float* __restrict__ out,
    int n)
{
    __shared__ float xs[K_SEG + 1];
    for (int i = threadIdx.x; i < K_SEG + 1; i += blockDim.x) xs[i] = x[i];
    __syncthreads();
    const float xlast = xs[K_SEG];
    const int tstride = gridDim.x * blockDim.x;
    for (int i = blockIdx.x * blockDim.x + threadIdx.x; i < n; i += tstride) {
        float xt = fmodf(xe[i], xlast);
        int lo = 0, hi = K_SEG - 1;
        while (lo < hi) {
            int mid = (lo + hi + 1) >> 1;
            if (xs[mid] <= xt) lo = mid; else hi = mid - 1;
        }
        int seg = lo;
        float x0 = xs[seg];
        float s  = (xt - x0) / (xs[seg + 1] - x0);
        float ts = 1.0f - s;
        float comb[8] = {1.f, 7.f, 21.f, 35.f, 35.f, 21.f, 7.f, 1.f};
        float a0 = 0.f, a1 = 0.f, a2 = 0.f;
        float sp = 1.f;
        float tp[8];
        tp[7] = 1.f;
        for (int j = 6; j >= 0; --j) tp[j] = tp[j + 1] * ts;
        for (int j = 0; j < 8; ++j) {
            float wj = comb[j] * sp * tp[j];
            a0 = fmaf(wj, cp[seg * 24 + j * 3 + 0], a0);
            a1 = fmaf(wj, cp[seg * 24 + j * 3 + 1], a1);
            a2 = fmaf(wj, cp[seg * 24 + j * 3 + 2], a2);
            sp *= s;
        }
        out[i * 3 + 0] = a0;
        out[i * 3 + 1] = a1;
        out[i * 3 + 2] = a2;
    }
}

extern "C" void kernel_launch(void* const* d_in, const int* in_sizes, int n_in,
                              void* d_out, int out_size, void* d_ws, size_t ws_size,
                              hipStream_t stream) {
    const float* x  = (const float*)d_in[0];   // (K+1,)
    const float* cp = (const float*)d_in[1];   // (K, 8, 3)
    const float* xe = (const float*)d_in[2];   // (N_EVAL,)
    float* out = (float*)d_out;                // (N_EVAL, 3)
    int n = in_sizes[2];

    const size_t btab_bytes = (size_t)M_BKT * sizeof(BEntry);   // 128 KB
    const size_t segt_bytes = (size_t)K_SEG * 64;               // 256 KB

    if (ws_size >= btab_bytes + segt_bytes) {
        BEntry* btab = (BEntry*)d_ws;
        float4* segt = (float4*)((char*)d_ws + btab_bytes);
        build_bucket_kernel<<<(M_BKT + 255) / 256, 256, 0, stream>>>(x, btab);
        build_segline_kernel<<<(K_SEG + 255) / 256, 256, 0, stream>>>(x, cp, segt);
        bezier_eval_line<<<256, 1024, 0, stream>>>(x, btab, segt, xe, out, n);
    } else {
        bezier_eval_fallback<<<2048, 256, 0, stream>>>(x, cp, xe, out, n);
    }
}